// Round 1
// baseline (1597.998 us; speedup 1.0000x reference)
//
#include <hip/hip_runtime.h>

static constexpr int HWn = 196;   // 14*14
static constexpr int NN  = 9;     // nodes
static constexpr int Cn  = 512;   // node dim
static constexpr int CBn = 1024;  // backbone dim
static constexpr int Dn  = 128;   // lstm dim
static constexpr int BTn = 128;   // B*T

__device__ __forceinline__ float sigm(float x) { return 1.f / (1.f + expf(-x)); }

__device__ __forceinline__ float waveSum(float v) {
#pragma unroll
  for (int o = 32; o > 0; o >>= 1) v += __shfl_down(v, o, 64);
  return v;
}
__device__ __forceinline__ float waveMax(float v) {
#pragma unroll
  for (int o = 32; o > 0; o >>= 1) v = fmaxf(v, __shfl_down(v, o, 64));
  return v;
}
// block reductions; red is shared scratch (>=4 floats). Must be called by all threads.
__device__ __forceinline__ float blockSum(float v, float* red) {
  const int lane = threadIdx.x & 63, wid = threadIdx.x >> 6;
  const int nw = blockDim.x >> 6;
  v = waveSum(v);
  __syncthreads();
  if (lane == 0) red[wid] = v;
  __syncthreads();
  float r = 0.f;
  for (int i = 0; i < nw; ++i) r += red[i];
  return r;
}
__device__ __forceinline__ float blockMax(float v, float* red) {
  const int lane = threadIdx.x & 63, wid = threadIdx.x >> 6;
  const int nw = blockDim.x >> 6;
  v = waveMax(v);
  __syncthreads();
  if (lane == 0) red[wid] = v;
  __syncthreads();
  float r = -3.4e38f;
  for (int i = 0; i < nw; ++i) r = fmaxf(r, red[i]);
  return r;
}

// ---------------- GEMM1: feat[r, o] = sum_c W_proj[o,c] * x[b,c,hw] + b_proj[o]
// r = b*196+hw; A is M-contiguous (column-major): A[r,k] = x[b*CB*196 + k*196 + hw]
__global__ __launch_bounds__(256) void k_feat(const float* __restrict__ x,
                                              const float* __restrict__ Wp,
                                              const float* __restrict__ bp,
                                              float* __restrict__ feat) {
  __shared__ __align__(16) float As[16][68];
  __shared__ __align__(16) float Ws[16][68];
  const int m0 = blockIdx.x * 64, n0 = blockIdx.y * 64;
  const int tid = threadIdx.x, tn = tid & 15, tm = tid >> 4;
  const int mrow = tid & 63, kq = tid >> 6;  // A staging
  const int r = m0 + mrow, bb = r / HWn, hw = r % HWn;
  const float* xb = x + (size_t)bb * CBn * HWn + hw;
  const int lr = tid >> 2, lc4 = (tid & 3) << 2;  // W staging
  float acc[4][4] = {};
  for (int k0 = 0; k0 < CBn; k0 += 16) {
#pragma unroll
    for (int p = 0; p < 4; ++p)
      As[kq * 4 + p][mrow] = xb[(size_t)(k0 + kq * 4 + p) * HWn];
    const float4 w = *(const float4*)&Wp[(size_t)(n0 + lr) * CBn + k0 + lc4];
    Ws[lc4 + 0][lr] = w.x; Ws[lc4 + 1][lr] = w.y; Ws[lc4 + 2][lr] = w.z; Ws[lc4 + 3][lr] = w.w;
    __syncthreads();
#pragma unroll
    for (int k = 0; k < 16; ++k) {
      const float4 a4 = *(const float4*)&As[k][tm << 2];
      const float4 b4 = *(const float4*)&Ws[k][tn << 2];
      const float av[4] = {a4.x, a4.y, a4.z, a4.w};
      const float bv[4] = {b4.x, b4.y, b4.z, b4.w};
#pragma unroll
      for (int i = 0; i < 4; ++i)
#pragma unroll
        for (int j = 0; j < 4; ++j) acc[i][j] += av[i] * bv[j];
    }
    __syncthreads();
  }
#pragma unroll
  for (int i = 0; i < 4; ++i) {
    const int m = m0 + tm * 4 + i;
    const int n = n0 + tn * 4;
    float4 v = make_float4(acc[i][0] + bp[n], acc[i][1] + bp[n + 1],
                           acc[i][2] + bp[n + 2], acc[i][3] + bp[n + 3]);
    *(float4*)&feat[(size_t)m * Cn + n] = v;
  }
}

// ---------------- generic GEMM: C[m,n] = sum_k A[m,k]*W[n,k] (+bias)(relu)(+resid)
template <int BIAS, int RELU, int RESID>
__global__ __launch_bounds__(256) void k_gemm(const float* __restrict__ A,
                                              const float* __restrict__ W,
                                              const float* __restrict__ bias,
                                              const float* __restrict__ resid,
                                              float* __restrict__ C,
                                              int M, int N, int K) {
  __shared__ __align__(16) float As[16][68];
  __shared__ __align__(16) float Ws[16][68];
  const int m0 = blockIdx.x * 64, n0 = blockIdx.y * 64;
  const int tid = threadIdx.x, tn = tid & 15, tm = tid >> 4;
  const int lr = tid >> 2, lc4 = (tid & 3) << 2;
  float acc[4][4] = {};
  for (int k0 = 0; k0 < K; k0 += 16) {
    float4 a = make_float4(0.f, 0.f, 0.f, 0.f);
    if (m0 + lr < M) a = *(const float4*)&A[(size_t)(m0 + lr) * K + k0 + lc4];
    As[lc4 + 0][lr] = a.x; As[lc4 + 1][lr] = a.y; As[lc4 + 2][lr] = a.z; As[lc4 + 3][lr] = a.w;
    const float4 w = *(const float4*)&W[(size_t)(n0 + lr) * K + k0 + lc4];
    Ws[lc4 + 0][lr] = w.x; Ws[lc4 + 1][lr] = w.y; Ws[lc4 + 2][lr] = w.z; Ws[lc4 + 3][lr] = w.w;
    __syncthreads();
#pragma unroll
    for (int k = 0; k < 16; ++k) {
      const float4 a4 = *(const float4*)&As[k][tm << 2];
      const float4 b4 = *(const float4*)&Ws[k][tn << 2];
      const float av[4] = {a4.x, a4.y, a4.z, a4.w};
      const float bv[4] = {b4.x, b4.y, b4.z, b4.w};
#pragma unroll
      for (int i = 0; i < 4; ++i)
#pragma unroll
        for (int j = 0; j < 4; ++j) acc[i][j] += av[i] * bv[j];
    }
    __syncthreads();
  }
#pragma unroll
  for (int i = 0; i < 4; ++i) {
    const int m = m0 + tm * 4 + i;
    if (m >= M) continue;
    const int n = n0 + tn * 4;
    float4 v = make_float4(acc[i][0], acc[i][1], acc[i][2], acc[i][3]);
    if (BIAS) { v.x += bias[n]; v.y += bias[n + 1]; v.z += bias[n + 2]; v.w += bias[n + 3]; }
    if (RELU) {
      v.x = fmaxf(v.x, 0.f); v.y = fmaxf(v.y, 0.f);
      v.z = fmaxf(v.z, 0.f); v.w = fmaxf(v.w, 0.f);
    }
    if (RESID) {
      const float4 rr = *(const float4*)&resid[(size_t)m * N + n];
      v.x += rr.x; v.y += rr.y; v.z += rr.z; v.w += rr.w;
    }
    *(float4*)&C[(size_t)m * N + n] = v;
  }
}

// ---------------- final: out[b,o,hw] = x + sum_c W_back[o,c]*om[r,c] + b_back[o]
__global__ __launch_bounds__(256) void k_back(const float* __restrict__ om,
                                              const float* __restrict__ Wb,
                                              const float* __restrict__ bb,
                                              const float* __restrict__ x,
                                              float* __restrict__ out) {
  __shared__ __align__(16) float As[16][68];
  __shared__ __align__(16) float Ws[16][68];
  __shared__ __align__(16) float Ct[64][68];
  const int m0 = blockIdx.x * 64, n0 = blockIdx.y * 64;
  const int tid = threadIdx.x, tn = tid & 15, tm = tid >> 4;
  const int lr = tid >> 2, lc4 = (tid & 3) << 2;
  float acc[4][4] = {};
  for (int k0 = 0; k0 < Cn; k0 += 16) {
    const float4 a = *(const float4*)&om[(size_t)(m0 + lr) * Cn + k0 + lc4];
    As[lc4 + 0][lr] = a.x; As[lc4 + 1][lr] = a.y; As[lc4 + 2][lr] = a.z; As[lc4 + 3][lr] = a.w;
    const float4 w = *(const float4*)&Wb[(size_t)(n0 + lr) * Cn + k0 + lc4];
    Ws[lc4 + 0][lr] = w.x; Ws[lc4 + 1][lr] = w.y; Ws[lc4 + 2][lr] = w.z; Ws[lc4 + 3][lr] = w.w;
    __syncthreads();
#pragma unroll
    for (int k = 0; k < 16; ++k) {
      const float4 a4 = *(const float4*)&As[k][tm << 2];
      const float4 b4 = *(const float4*)&Ws[k][tn << 2];
      const float av[4] = {a4.x, a4.y, a4.z, a4.w};
      const float bv[4] = {b4.x, b4.y, b4.z, b4.w};
#pragma unroll
      for (int i = 0; i < 4; ++i)
#pragma unroll
        for (int j = 0; j < 4; ++j) acc[i][j] += av[i] * bv[j];
    }
    __syncthreads();
  }
#pragma unroll
  for (int i = 0; i < 4; ++i)
#pragma unroll
    for (int j = 0; j < 4; ++j) Ct[tn * 4 + j][tm * 4 + i] = acc[i][j];
  __syncthreads();
  const int ml = tid & 63;
  const int r = m0 + ml, bb2 = r / HWn, hw2 = r % HWn;
#pragma unroll
  for (int q = 0; q < 16; ++q) {
    const int ol = (tid >> 6) + q * 4;
    const int o = n0 + ol;
    const size_t adr = ((size_t)bb2 * CBn + o) * HWn + hw2;
    out[adr] = x[adr] + Ct[ol][ml] + bb[o];
  }
}

// ---------------- attention pooling: logits -> softmax over hw -> attw
__global__ __launch_bounds__(256) void k_attnpool(const float* __restrict__ feat,
                                                  const float* __restrict__ Wattn,
                                                  float* __restrict__ attw) {
  __shared__ float S[HWn][65];
  __shared__ float Wa[NN][64];
  __shared__ float L[NN][HWn];
  __shared__ float red[4];
  const int bt = blockIdx.x, tid = threadIdx.x;
  float lacc[NN];
#pragma unroll
  for (int n = 0; n < NN; ++n) lacc[n] = 0.f;
  const float* fb = feat + (size_t)bt * HWn * Cn;
  const int srow = tid >> 4, sc4 = (tid & 15) << 2;
  for (int c0 = 0; c0 < Cn; c0 += 64) {
    for (int rr = srow; rr < HWn; rr += 16) {
      const float4 f = *(const float4*)&fb[(size_t)rr * Cn + c0 + sc4];
      S[rr][sc4] = f.x; S[rr][sc4 + 1] = f.y; S[rr][sc4 + 2] = f.z; S[rr][sc4 + 3] = f.w;
    }
    for (int idx = tid; idx < NN * 64; idx += 256)
      Wa[idx >> 6][idx & 63] = Wattn[(size_t)(idx >> 6) * Cn + c0 + (idx & 63)];
    __syncthreads();
    if (tid < HWn) {
      for (int c = 0; c < 64; ++c) {
        const float s = S[tid][c];
#pragma unroll
        for (int n = 0; n < NN; ++n) lacc[n] += Wa[n][c] * s;
      }
    }
    __syncthreads();
  }
  if (tid < HWn)
#pragma unroll
    for (int n = 0; n < NN; ++n) L[n][tid] = lacc[n];
  __syncthreads();
  for (int n = 0; n < NN; ++n) {
    const float v = (tid < HWn) ? L[n][tid] : -3.4e38f;
    const float mx = blockMax(v, red);
    const float e = (tid < HWn) ? expf(v - mx) : 0.f;
    const float s = blockSum(e, red);
    if (tid < HWn) attw[((size_t)bt * NN + n) * HWn + tid] = e / s;
  }
}

// ---------------- gf[bt,n,c] = sum_hw attw * feat
__global__ __launch_bounds__(256) void k_gf(const float* __restrict__ feat,
                                            const float* __restrict__ attw,
                                            float* __restrict__ gf) {
  __shared__ float aw[NN][HWn];
  const int bt = blockIdx.x, tid = threadIdx.x;
  for (int idx = tid; idx < NN * HWn; idx += 256)
    aw[idx / HWn][idx % HWn] = attw[(size_t)bt * NN * HWn + idx];
  __syncthreads();
  float a0[NN] = {}, a1[NN] = {};
  const float* fb = feat + (size_t)bt * HWn * Cn;
  for (int hw = 0; hw < HWn; ++hw) {
    const float f0 = fb[(size_t)hw * Cn + tid];
    const float f1 = fb[(size_t)hw * Cn + tid + 256];
#pragma unroll
    for (int n = 0; n < NN; ++n) {
      const float w = aw[n][hw];
      a0[n] += w * f0; a1[n] += w * f1;
    }
  }
#pragma unroll
  for (int n = 0; n < NN; ++n) {
    gf[((size_t)bt * NN + n) * Cn + tid] = a0[n];
    gf[((size_t)bt * NN + n) * Cn + tid + 256] = a1[n];
  }
}

// ---------------- gf2 = LN(gf @ W_gf^T + b_gf) * g1 + beta1  (one block per (bt,n))
__global__ __launch_bounds__(128) void k_gfln(const float* __restrict__ gf,
                                              const float* __restrict__ Wgf,
                                              const float* __restrict__ bgf,
                                              const float* __restrict__ g1,
                                              const float* __restrict__ beta1,
                                              float* __restrict__ gf2) {
  __shared__ __align__(16) float src[Cn];
  __shared__ float red[4];
  const int row = blockIdx.x;   // bt*9+n
  const int n = row % NN;
  const int tid = threadIdx.x;  // 128
  for (int i = tid; i < Cn; i += 128) src[i] = gf[(size_t)row * Cn + i];
  __syncthreads();
  float acc = bgf[tid];
  const float* wr = Wgf + (size_t)tid * Cn;
  for (int c = 0; c < Cn; c += 4) {
    const float4 w = *(const float4*)&wr[c];
    acc += w.x * src[c] + w.y * src[c + 1] + w.z * src[c + 2] + w.w * src[c + 3];
  }
  const float mean = blockSum(acc, red) * (1.f / 128.f);
  const float d = acc - mean;
  const float var = blockSum(d * d, red) * (1.f / 128.f);
  gf2[(size_t)row * Dn + tid] =
      d * rsqrtf(var + 1e-5f) * g1[n * Dn + tid] + beta1[n * Dn + tid];
}

// ---------------- LSTM over T=8, one block per (b,n)
__global__ __launch_bounds__(256) void k_lstm(const float* __restrict__ xW,
                                              const float* __restrict__ Whh,
                                              const float* __restrict__ bhh,
                                              float* __restrict__ ys) {
  __shared__ __align__(16) float h[Dn];
  __shared__ float cc[Dn];
  __shared__ float gates[4 * Dn];
  const int blk = blockIdx.x, b = blk / NN, n = blk % NN;
  const int tid = threadIdx.x;
  if (tid < Dn) { h[tid] = 0.f; cc[tid] = 0.f; }
  __syncthreads();
  for (int t = 0; t < 8; ++t) {
    const int bt = b * 8 + t;
    const size_t xrow = ((size_t)bt * NN + n) * (4 * Dn);
#pragma unroll
    for (int gq = 0; gq < 2; ++gq) {
      const int g = tid + gq * 256;
      float acc = xW[xrow + g] + bhh[g];
      const float* wr = Whh + (size_t)g * Dn;
#pragma unroll 8
      for (int d = 0; d < Dn; d += 4) {
        const float4 w = *(const float4*)&wr[d];
        acc += w.x * h[d] + w.y * h[d + 1] + w.z * h[d + 2] + w.w * h[d + 3];
      }
      gates[g] = acc;
    }
    __syncthreads();
    if (tid < Dn) {
      const float ig = sigm(gates[tid]);
      const float fg = sigm(gates[Dn + tid]);
      const float gg = tanhf(gates[2 * Dn + tid]);
      const float og = sigm(gates[3 * Dn + tid]);
      const float cn = fg * cc[tid] + ig * gg;
      const float hn = og * tanhf(cn);
      cc[tid] = cn; h[tid] = hn;
      ys[((size_t)bt * NN + n) * Dn + tid] = hn;
    }
    __syncthreads();
  }
}

// ---------------- offsets -> khs/kws, one block per (bt,n)
__global__ __launch_bounds__(128) void k_off(const float* __restrict__ ys,
                                             const float* __restrict__ g2,
                                             const float* __restrict__ beta2,
                                             const float* __restrict__ Wpred,
                                             const float* __restrict__ bpred,
                                             const float* __restrict__ alpha,
                                             float* __restrict__ khs,
                                             float* __restrict__ kws) {
  __shared__ float red[4];
  __shared__ float cpar[4];  // ch, cw, sh, sw
  const int row = blockIdx.x;  // bt*9+n
  const int n = row % NN;
  const int tid = threadIdx.x;
  const float y = ys[(size_t)row * Dn + tid];
  const float mean = blockSum(y, red) * (1.f / 128.f);
  const float d = y - mean;
  const float var = blockSum(d * d, red) * (1.f / 128.f);
  const float v = d * rsqrtf(var + 1e-5f) * g2[n * Dn + tid] + beta2[n * Dn + tid];
  const float o0 = blockSum(v * Wpred[0 * Dn + tid], red);
  const float o1 = blockSum(v * Wpred[1 * Dn + tid], red);
  const float o2 = blockSum(v * Wpred[2 * Dn + tid], red);
  const float o3 = blockSum(v * Wpred[3 * Dn + tid], red);
  if (tid == 0) {
    const float f0 = (o0 + bpred[0]) * alpha[0];
    const float f1 = (o1 + bpred[1]) * alpha[1];
    const float f2 = (o2 + bpred[2]) * alpha[2];
    const float f3 = (o3 + bpred[3]) * alpha[3];
    const float ph0 = ((n / 3) + 0.5f) * (14.f / 3.f);
    const float pw0 = ((n % 3) + 0.5f) * (14.f / 3.f);
    cpar[0] = ph0 + f0;
    cpar[1] = pw0 + f1;
    cpar[2] = (14.f / 3.f) * expf(f2);
    cpar[3] = (14.f / 3.f) * expf(f3);
  }
  __syncthreads();
  if (tid < 14) {
    float s = 0.f;
#pragma unroll
    for (int i = 0; i < 3; ++i) {
      const float rel = (i + 0.5f) / 3.f - 0.5f;
      const float p = cpar[0] + cpar[2] * rel;
      s += fmaxf(1.f - fabsf(p - (float)tid), 0.f);
    }
    khs[(size_t)row * 14 + tid] = s;
  } else if (tid < 28) {
    const int H = tid - 14;
    float s = 0.f;
#pragma unroll
    for (int i = 0; i < 3; ++i) {
      const float rel = (i + 0.5f) / 3.f - 0.5f;
      const float p = cpar[1] + cpar[3] * rel;
      s += fmaxf(1.f - fabsf(p - (float)H), 0.f);
    }
    kws[(size_t)row * 14 + H] = s;
  }
}

// ---------------- transpose W_kp1 [512,196] -> [196,512]
__global__ __launch_bounds__(256) void k_wkp1t(const float* __restrict__ Wkp1,
                                               float* __restrict__ wkT) {
  const int hw = blockIdx.x, c = threadIdx.x;
  wkT[(size_t)hw * Cn + c] = Wkp1[(size_t)c * HWn + hw];
  wkT[(size_t)hw * Cn + c + 256] = Wkp1[(size_t)(c + 256) * HWn + hw];
}

// ---------------- nodes = samp + kern2d @ W_kp1^T + b_kp1  (one block per bt)
__global__ __launch_bounds__(256) void k_nodes(const float* __restrict__ feat,
                                               const float* __restrict__ wkT,
                                               const float* __restrict__ khs,
                                               const float* __restrict__ kws,
                                               const float* __restrict__ bkp1,
                                               float* __restrict__ nodes) {
  __shared__ float kh[NN][14], kw[NN][14];
  const int bt = blockIdx.x, tid = threadIdx.x;
  if (tid < NN * 14) {
    kh[tid / 14][tid % 14] = khs[(size_t)bt * NN * 14 + tid];
    kw[tid / 14][tid % 14] = kws[(size_t)bt * NN * 14 + tid];
  }
  __syncthreads();
  float a0[NN] = {}, a1[NN] = {};
  const float* fb = feat + (size_t)bt * HWn * Cn;
  for (int hw = 0; hw < HWn; ++hw) {
    const int Hh = hw / 14, Ll = hw % 14;
    const float f0 = fb[(size_t)hw * Cn + tid] * (1.f / 9.f) + wkT[(size_t)hw * Cn + tid];
    const float f1 = fb[(size_t)hw * Cn + tid + 256] * (1.f / 9.f) + wkT[(size_t)hw * Cn + tid + 256];
#pragma unroll
    for (int n = 0; n < NN; ++n) {
      const float w = kh[n][Hh] * kw[n][Ll];
      a0[n] += w * f0; a1[n] += w * f1;
    }
  }
#pragma unroll
  for (int n = 0; n < NN; ++n) {
    nodes[((size_t)bt * NN + n) * Cn + tid] = a0[n] + bkp1[tid];
    nodes[((size_t)bt * NN + n) * Cn + tid + 256] = a1[n] + bkp1[tid + 256];
  }
}

// ---------------- per-(b,t) 9x9 graph attention: agg = softmax(qk^T/sqrt(C)) v
__global__ __launch_bounds__(256) void k_att(const float* __restrict__ q,
                                             const float* __restrict__ k,
                                             const float* __restrict__ v,
                                             float* __restrict__ agg) {
  __shared__ __align__(16) float qs[NN][Cn];
  __shared__ __align__(16) float ks[NN][Cn];
  __shared__ __align__(16) float vs[NN][Cn];
  __shared__ float s[NN][NN];
  const int bt = blockIdx.x, tid = threadIdx.x;
  const size_t base = (size_t)bt * NN * Cn;
  for (int idx = tid; idx < NN * Cn; idx += 256) {
    qs[idx / Cn][idx % Cn] = q[base + idx];
    ks[idx / Cn][idx % Cn] = k[base + idx];
    vs[idx / Cn][idx % Cn] = v[base + idx];
  }
  __syncthreads();
  if (tid < NN * NN) {
    const int i = tid / NN, j = tid % NN;
    float acc = 0.f;
    for (int c = 0; c < Cn; c += 4) {
      const float4 qa = *(const float4*)&qs[i][c];
      const float4 kb = *(const float4*)&ks[j][c];
      acc += qa.x * kb.x + qa.y * kb.y + qa.z * kb.z + qa.w * kb.w;
    }
    s[i][j] = acc * 0.044194173824159216f;  // 1/sqrt(512)
  }
  __syncthreads();
  if (tid < NN) {
    float mx = -3.4e38f;
#pragma unroll
    for (int j = 0; j < NN; ++j) mx = fmaxf(mx, s[tid][j]);
    float sum = 0.f;
#pragma unroll
    for (int j = 0; j < NN; ++j) { const float e = expf(s[tid][j] - mx); s[tid][j] = e; sum += e; }
    const float inv = 1.f / sum;
#pragma unroll
    for (int j = 0; j < NN; ++j) s[tid][j] *= inv;
  }
  __syncthreads();
  for (int c = tid; c < Cn; c += 256) {
#pragma unroll
    for (int i = 0; i < NN; ++i) {
      float acc = 0.f;
#pragma unroll
      for (int j = 0; j < NN; ++j) acc += s[i][j] * vs[j][c];
      agg[((size_t)bt * NN + i) * Cn + c] = acc;
    }
  }
}

// ---------------- GRU elementwise update
template <int T0>
__global__ __launch_bounds__(256) void k_gruupd(const float* __restrict__ gi,
                                                const float* __restrict__ gh,
                                                const float* __restrict__ bghh,
                                                float* __restrict__ hgru,
                                                float* __restrict__ out_nodes,
                                                int t) {
  const int idx = blockIdx.x * 256 + threadIdx.x;  // 144*512
  const int row = idx >> 9, d = idx & 511;
  const int b = row / NN, n = row % NN;
  const size_t girow = ((size_t)(b * 8 + t) * NN + n) * (3 * Cn);
  const float ir = gi[girow + d], iz = gi[girow + Cn + d], ig = gi[girow + 2 * Cn + d];
  float hr, hz, hg, hp;
  if (T0) {
    hr = bghh[d]; hz = bghh[Cn + d]; hg = bghh[2 * Cn + d]; hp = 0.f;
  } else {
    const size_t gr = (size_t)row * (3 * Cn);
    hr = gh[gr + d]; hz = gh[gr + Cn + d]; hg = gh[gr + 2 * Cn + d];
    hp = hgru[(size_t)row * Cn + d];
  }
  const float rg = sigm(ir + hr);
  const float zg = sigm(iz + hz);
  const float ng = tanhf(ig + rg * hg);
  const float h = (1.f - zg) * ng + zg * hp;
  hgru[(size_t)row * Cn + d] = h;
  out_nodes[((size_t)(b * 8 + t) * NN + n) * Cn + d] = h;
}

// ---------------- remap nodes to spatial map: om[r, c] = num/den
__global__ __launch_bounds__(256) void k_remap(const float* __restrict__ out_nodes,
                                               const float* __restrict__ khs,
                                               const float* __restrict__ kws,
                                               float* __restrict__ om) {
  __shared__ __align__(16) float on[NN][Cn];
  __shared__ float kh[NN][14], kw[NN][14];
  const int bt = blockIdx.x, tid = threadIdx.x;
  for (int idx = tid; idx < NN * Cn; idx += 256)
    on[idx / Cn][idx % Cn] = out_nodes[(size_t)bt * NN * Cn + idx];
  if (tid < NN * 14) {
    kh[tid / 14][tid % 14] = khs[(size_t)bt * NN * 14 + tid];
    kw[tid / 14][tid % 14] = kws[(size_t)bt * NN * 14 + tid];
  }
  __syncthreads();
  for (int hw = 0; hw < HWn; ++hw) {
    const int Hh = hw / 14, Ll = hw % 14;
    float w[NN];
    float den = 1e-6f;
#pragma unroll
    for (int n = 0; n < NN; ++n) { w[n] = kh[n][Hh] * kw[n][Ll]; den += w[n]; }
    const float inv = 1.f / den;
    float s0 = 0.f, s1 = 0.f;
#pragma unroll
    for (int n = 0; n < NN; ++n) {
      s0 += on[n][tid] * w[n];
      s1 += on[n][tid + 256] * w[n];
    }
    om[((size_t)bt * HWn + hw) * Cn + tid] = s0 * inv;
    om[((size_t)bt * HWn + hw) * Cn + tid + 256] = s1 * inv;
  }
}

extern "C" void kernel_launch(void* const* d_in, const int* in_sizes, int n_in,
                              void* d_out, int out_size, void* d_ws, size_t ws_size,
                              hipStream_t stream) {
  const float* x      = (const float*)d_in[0];
  const float* W_proj = (const float*)d_in[1];
  const float* b_proj = (const float*)d_in[2];
  const float* W_attn = (const float*)d_in[3];
  const float* W_gf   = (const float*)d_in[4];
  const float* b_gf   = (const float*)d_in[5];
  const float* g1     = (const float*)d_in[6];
  const float* beta1  = (const float*)d_in[7];
  const float* g2     = (const float*)d_in[8];
  const float* beta2  = (const float*)d_in[9];
  const float* W_ih   = (const float*)d_in[10];
  const float* W_hh   = (const float*)d_in[11];
  const float* b_ih   = (const float*)d_in[12];
  const float* b_hh   = (const float*)d_in[13];
  const float* W_pred = (const float*)d_in[14];
  const float* b_pred = (const float*)d_in[15];
  const float* alpha  = (const float*)d_in[16];
  const float* W_kp1  = (const float*)d_in[17];
  const float* b_kp1  = (const float*)d_in[18];
  const float* Wq     = (const float*)d_in[19];
  const float* Wk     = (const float*)d_in[20];
  const float* Wv     = (const float*)d_in[21];
  const float* Wu     = (const float*)d_in[22];
  const float* b_u    = (const float*)d_in[23];
  const float* W_gih  = (const float*)d_in[24];
  const float* W_ghh  = (const float*)d_in[25];
  const float* b_gih  = (const float*)d_in[26];
  const float* b_ghh  = (const float*)d_in[27];
  const float* W_back = (const float*)d_in[28];
  const float* b_back = (const float*)d_in[29];
  float* out = (float*)d_out;

  float* ws = (float*)d_ws;
  size_t off = 0;
  float* feat      = ws + off; off += (size_t)25088 * 512;   // 12,845,056
  float* attw      = ws + off; off += (size_t)BTn * NN * HWn; // 225,792
  float* gf        = ws + off; off += (size_t)BTn * NN * Cn;  // 589,824
  float* gf2       = ws + off; off += (size_t)BTn * NN * Dn;  // 147,456
  float* xW        = ws + off; off += (size_t)BTn * NN * 512; // 589,824
  float* ys        = ws + off; off += (size_t)BTn * NN * Dn;  // 147,456
  float* khs       = ws + off; off += (size_t)BTn * NN * 14;  // 16,128
  float* kws       = ws + off; off += (size_t)BTn * NN * 14;  // 16,128
  float* nodes     = ws + off; off += (size_t)BTn * NN * Cn;
  float* qb        = ws + off; off += (size_t)BTn * NN * Cn;
  float* kb        = ws + off; off += (size_t)BTn * NN * Cn;
  float* vb        = ws + off; off += (size_t)BTn * NN * Cn;
  float* aggb      = ws + off; off += (size_t)BTn * NN * Cn;
  float* nd2       = ws + off; off += (size_t)BTn * NN * Cn;
  float* gi        = ws + off; off += (size_t)BTn * NN * 3 * Cn; // 1,769,472
  float* hgru      = ws + off; off += (size_t)144 * Cn;          // 73,728
  float* gh        = ws + off; off += (size_t)144 * 3 * Cn;      // 221,184
  float* wkT       = ws + off; off += (size_t)HWn * Cn;          // 100,352
  float* out_nodes = ws + off; off += (size_t)BTn * NN * Cn;
  float* om        = feat;  // feat is dead after k_nodes; reuse for out_map

  // 1. backbone projection: feat[r=(bt,hw), o]
  k_feat<<<dim3(392, 8), 256, 0, stream>>>(x, W_proj, b_proj, feat);
  // 2. attention pooling weights (logits + softmax over hw)
  k_attnpool<<<BTn, 256, 0, stream>>>(feat, W_attn, attw);
  // 3. gf = attw-weighted pooling of feat
  k_gf<<<BTn, 256, 0, stream>>>(feat, attw, gf);
  // 4. gf2 = LN(gf @ W_gf^T + b_gf)
  k_gfln<<<BTn * NN, 128, 0, stream>>>(gf, W_gf, b_gf, g1, beta1, gf2);
  // 5. LSTM input GEMM (batched over all t)
  k_gemm<1, 0, 0><<<dim3(18, 8), 256, 0, stream>>>(gf2, W_ih, b_ih, nullptr, xW, 1152, 512, 128);
  // 6. LSTM recurrence
  k_lstm<<<144, 256, 0, stream>>>(xW, W_hh, b_hh, ys);
  // 7. offsets -> sampling kernels khs/kws
  k_off<<<BTn * NN, 128, 0, stream>>>(ys, g2, beta2, W_pred, b_pred, alpha, khs, kws);
  // 8. transpose W_kp1 for coalesced access
  k_wkp1t<<<HWn, 256, 0, stream>>>(W_kp1, wkT);
  // 9. nodes = crop-pool + kernel-location embedding
  k_nodes<<<BTn, 256, 0, stream>>>(feat, wkT, khs, kws, b_kp1, nodes);
  // 10. q/k/v projections
  k_gemm<0, 0, 0><<<dim3(18, 8), 256, 0, stream>>>(nodes, Wq, nullptr, nullptr, qb, 1152, 512, 512);
  k_gemm<0, 0, 0><<<dim3(18, 8), 256, 0, stream>>>(nodes, Wk, nullptr, nullptr, kb, 1152, 512, 512);
  k_gemm<0, 0, 0><<<dim3(18, 8), 256, 0, stream>>>(nodes, Wv, nullptr, nullptr, vb, 1152, 512, 512);
  // 11. 9x9 graph attention
  k_att<<<BTn, 256, 0, stream>>>(qb, kb, vb, aggb);
  // 12. nd2 = nodes + relu(agg @ Wu^T + b_u)
  k_gemm<1, 1, 1><<<dim3(18, 8), 256, 0, stream>>>(aggb, Wu, b_u, nodes, nd2, 1152, 512, 512);
  // 13. GRU input GEMM (batched over all t)
  k_gemm<1, 0, 0><<<dim3(18, 24), 256, 0, stream>>>(nd2, W_gih, b_gih, nullptr, gi, 1152, 1536, 512);
  // 14. GRU recurrence: per-step hidden GEMM + update
  for (int t = 0; t < 8; ++t) {
    if (t > 0)
      k_gemm<1, 0, 0><<<dim3(3, 24), 256, 0, stream>>>(hgru, W_ghh, b_ghh, nullptr, gh, 144, 1536, 512);
    if (t == 0)
      k_gruupd<1><<<288, 256, 0, stream>>>(gi, gh, b_ghh, hgru, out_nodes, t);
    else
      k_gruupd<0><<<288, 256, 0, stream>>>(gi, gh, b_ghh, hgru, out_nodes, t);
  }
  // 15. remap node states to spatial map (overwrites feat as om)
  k_remap<<<BTn, 256, 0, stream>>>(out_nodes, khs, kws, om);
  // 16. project back + residual
  k_back<<<dim3(392, 16), 256, 0, stream>>>(om, W_back, b_back, x, out);
}

// Round 2
// 1377.430 us; speedup vs baseline: 1.1601x; 1.1601x over previous
//
#include <hip/hip_runtime.h>

typedef unsigned short u16;
typedef __attribute__((ext_vector_type(8))) u16 b16x8;
typedef __attribute__((ext_vector_type(4))) float f32x4;

static constexpr int HWn = 196;   // 14*14
static constexpr int NN  = 9;     // nodes
static constexpr int Cn  = 512;   // node dim
static constexpr int CBn = 1024;  // backbone dim
static constexpr int Dn  = 128;   // lstm dim
static constexpr int BTn = 128;   // B*T

__device__ __forceinline__ float sigm(float x) { return 1.f / (1.f + expf(-x)); }

__device__ __forceinline__ u16 f2bf(float f) {
  unsigned int u = __builtin_bit_cast(unsigned int, f);
  u = (u + 0x7fff + ((u >> 16) & 1)) >> 16;  // RNE
  return (u16)u;
}

__device__ __forceinline__ float waveSum(float v) {
#pragma unroll
  for (int o = 32; o > 0; o >>= 1) v += __shfl_down(v, o, 64);
  return v;
}
__device__ __forceinline__ float waveMax(float v) {
#pragma unroll
  for (int o = 32; o > 0; o >>= 1) v = fmaxf(v, __shfl_down(v, o, 64));
  return v;
}
__device__ __forceinline__ float blockSum(float v, float* red) {
  const int lane = threadIdx.x & 63, wid = threadIdx.x >> 6;
  const int nw = blockDim.x >> 6;
  v = waveSum(v);
  __syncthreads();
  if (lane == 0) red[wid] = v;
  __syncthreads();
  float r = 0.f;
  for (int i = 0; i < nw; ++i) r += red[i];
  return r;
}
__device__ __forceinline__ float blockMax(float v, float* red) {
  const int lane = threadIdx.x & 63, wid = threadIdx.x >> 6;
  const int nw = blockDim.x >> 6;
  v = waveMax(v);
  __syncthreads();
  if (lane == 0) red[wid] = v;
  __syncthreads();
  float r = -3.4e38f;
  for (int i = 0; i < nw; ++i) r = fmaxf(r, red[i]);
  return r;
}

// ---------------- fp32 -> bf16 cast (weights)
__global__ __launch_bounds__(256) void k_cast(const float* __restrict__ in,
                                              u16* __restrict__ out, int n) {
  const int i = (blockIdx.x * 256 + threadIdx.x) * 4;
  if (i < n) {
    const float4 v = *(const float4*)&in[i];
    out[i + 0] = f2bf(v.x); out[i + 1] = f2bf(v.y);
    out[i + 2] = f2bf(v.z); out[i + 3] = f2bf(v.w);
  }
}

// ---------------- x[bt][c][hw] fp32 -> xT[(bt,hw)][c] bf16
__global__ __launch_bounds__(256) void k_xt(const float* __restrict__ x,
                                            u16* __restrict__ xT) {
  __shared__ u16 T[64][201];
  const int bt = blockIdx.x, c0 = blockIdx.y * 64, tid = threadIdx.x;
  const float* xb = x + ((size_t)bt * CBn + c0) * HWn;
  for (int idx = tid; idx < 64 * HWn; idx += 256)
    T[idx / HWn][idx % HWn] = f2bf(xb[idx]);
  __syncthreads();
  unsigned int* xTu = (unsigned int*)(xT + ((size_t)bt * HWn) * CBn + c0);
  for (int idx = tid; idx < HWn * 32; idx += 256) {
    const int hw = idx >> 5, j = idx & 31;
    const unsigned int lo = T[2 * j][hw], hi = T[2 * j + 1][hw];
    xTu[(size_t)hw * (CBn / 2) + j] = lo | (hi << 16);
  }
}

// ---------------- bf16 MFMA GEMM, 128x128 tile, C[m,n] = sum_k A[m,k]*B[n,k]
// MODE 0: C fp32 row-major [M,N], + bias[n]
// MODE 1: out[(m/196)*1024+n)*196 + m%196] = xres[same] + acc + bias[n]
template <int MODE>
__global__ __launch_bounds__(256) void k_mm128(const u16* __restrict__ A,
                                               const u16* __restrict__ B,
                                               const float* __restrict__ bias,
                                               const float* __restrict__ xres,
                                               float* __restrict__ C,
                                               const int M, const int N, const int K) {
  __shared__ __align__(16) u16 As[128 * 64];
  __shared__ __align__(16) u16 Bs[128 * 64];
  const int tid = threadIdx.x;
  const int lane = tid & 63;
  const int w = tid >> 6, wr = w >> 1, wc = w & 1;
  const int m0 = blockIdx.x * 128, n0 = blockIdx.y * 128;

  // staging: 4 chunks (16B) per thread; chunk = i*256+tid -> row=chunk>>3, c16=chunk&7
  int srow[4], slds[4], sc16[4];
#pragma unroll
  for (int i = 0; i < 4; ++i) {
    const int chunk = i * 256 + tid;
    const int row = chunk >> 3, c16 = chunk & 7;
    srow[i] = row; sc16[i] = c16;
    slds[i] = row * 64 + ((c16 ^ (row & 7)) << 3);  // XOR-swizzled 16B slot
  }
  uint4 ar[4], br[4];
#pragma unroll
  for (int i = 0; i < 4; ++i) {
    ar[i] = *(const uint4*)(A + (size_t)(m0 + srow[i]) * K + sc16[i] * 8);
    br[i] = *(const uint4*)(B + (size_t)(n0 + srow[i]) * K + sc16[i] * 8);
  }

  // fragment LDS offsets (u16 units), swizzle matched to writes
  int fa[4][2], fb[4][2];
#pragma unroll
  for (int q = 0; q < 4; ++q)
#pragma unroll
    for (int ks = 0; ks < 2; ++ks) {
      const int rowa = wr * 64 + q * 16 + (lane & 15);
      fa[q][ks] = rowa * 64 + (((ks * 4 + (lane >> 4)) ^ (rowa & 7)) << 3);
      const int rowb = wc * 64 + q * 16 + (lane & 15);
      fb[q][ks] = rowb * 64 + (((ks * 4 + (lane >> 4)) ^ (rowb & 7)) << 3);
    }

  f32x4 acc[4][4];
#pragma unroll
  for (int a = 0; a < 4; ++a)
#pragma unroll
    for (int b = 0; b < 4; ++b) acc[a][b] = f32x4{0.f, 0.f, 0.f, 0.f};

  for (int k0 = 0; k0 < K; k0 += 64) {
    __syncthreads();
#pragma unroll
    for (int i = 0; i < 4; ++i) {
      *(uint4*)&As[slds[i]] = ar[i];
      *(uint4*)&Bs[slds[i]] = br[i];
    }
    __syncthreads();
    const int kn = k0 + 64;
    if (kn < K) {
#pragma unroll
      for (int i = 0; i < 4; ++i) {
        ar[i] = *(const uint4*)(A + (size_t)(m0 + srow[i]) * K + kn + sc16[i] * 8);
        br[i] = *(const uint4*)(B + (size_t)(n0 + srow[i]) * K + kn + sc16[i] * 8);
      }
    }
    b16x8 af[4][2], bg[4][2];
#pragma unroll
    for (int q = 0; q < 4; ++q)
#pragma unroll
      for (int ks = 0; ks < 2; ++ks) {
        af[q][ks] = *(const b16x8*)&As[fa[q][ks]];
        bg[q][ks] = *(const b16x8*)&Bs[fb[q][ks]];
      }
#pragma unroll
    for (int ks = 0; ks < 2; ++ks)
#pragma unroll
      for (int mi = 0; mi < 4; ++mi)
#pragma unroll
        for (int nj = 0; nj < 4; ++nj)
          asm volatile("v_mfma_f32_16x16x32_bf16 %0, %1, %2, %0"
                       : "+v"(acc[mi][nj])
                       : "v"(af[mi][ks]), "v"(bg[nj][ks]));
  }

#pragma unroll
  for (int nj = 0; nj < 4; ++nj) {
    const int n = n0 + wc * 64 + nj * 16 + (lane & 15);
    const float bv = bias[n];
#pragma unroll
    for (int mi = 0; mi < 4; ++mi) {
#pragma unroll
      for (int r = 0; r < 4; ++r) {
        const int m = m0 + wr * 64 + mi * 16 + (lane >> 4) * 4 + r;
        if (MODE == 0) {
          C[(size_t)m * N + n] = acc[mi][nj][r] + bv;
        } else {
          const int b = m / HWn, hw = m - b * HWn;
          const size_t adr = ((size_t)b * CBn + n) * HWn + hw;
          C[adr] = xres[adr] + acc[mi][nj][r] + bv;
        }
      }
    }
  }
}

// ---------------- generic fp32 GEMM: C[m,n] = sum_k A[m,k]*W[n,k] (+bias)(relu)(+resid)
template <int BIAS, int RELU, int RESID>
__global__ __launch_bounds__(256) void k_gemm(const float* __restrict__ A,
                                              const float* __restrict__ W,
                                              const float* __restrict__ bias,
                                              const float* __restrict__ resid,
                                              float* __restrict__ C,
                                              int M, int N, int K) {
  __shared__ __align__(16) float As[16][68];
  __shared__ __align__(16) float Ws[16][68];
  const int m0 = blockIdx.x * 64, n0 = blockIdx.y * 64;
  const int tid = threadIdx.x, tn = tid & 15, tm = tid >> 4;
  const int lr = tid >> 2, lc4 = (tid & 3) << 2;
  float acc[4][4] = {};
  for (int k0 = 0; k0 < K; k0 += 16) {
    float4 a = make_float4(0.f, 0.f, 0.f, 0.f);
    if (m0 + lr < M) a = *(const float4*)&A[(size_t)(m0 + lr) * K + k0 + lc4];
    As[lc4 + 0][lr] = a.x; As[lc4 + 1][lr] = a.y; As[lc4 + 2][lr] = a.z; As[lc4 + 3][lr] = a.w;
    const float4 w = *(const float4*)&W[(size_t)(n0 + lr) * K + k0 + lc4];
    Ws[lc4 + 0][lr] = w.x; Ws[lc4 + 1][lr] = w.y; Ws[lc4 + 2][lr] = w.z; Ws[lc4 + 3][lr] = w.w;
    __syncthreads();
#pragma unroll
    for (int k = 0; k < 16; ++k) {
      const float4 a4 = *(const float4*)&As[k][tm << 2];
      const float4 b4 = *(const float4*)&Ws[k][tn << 2];
      const float av[4] = {a4.x, a4.y, a4.z, a4.w};
      const float bv[4] = {b4.x, b4.y, b4.z, b4.w};
#pragma unroll
      for (int i = 0; i < 4; ++i)
#pragma unroll
        for (int j = 0; j < 4; ++j) acc[i][j] += av[i] * bv[j];
    }
    __syncthreads();
  }
#pragma unroll
  for (int i = 0; i < 4; ++i) {
    const int m = m0 + tm * 4 + i;
    if (m >= M) continue;
    const int n = n0 + tn * 4;
    float4 v = make_float4(acc[i][0], acc[i][1], acc[i][2], acc[i][3]);
    if (BIAS) { v.x += bias[n]; v.y += bias[n + 1]; v.z += bias[n + 2]; v.w += bias[n + 3]; }
    if (RELU) {
      v.x = fmaxf(v.x, 0.f); v.y = fmaxf(v.y, 0.f);
      v.z = fmaxf(v.z, 0.f); v.w = fmaxf(v.w, 0.f);
    }
    if (RESID) {
      const float4 rr = *(const float4*)&resid[(size_t)m * N + n];
      v.x += rr.x; v.y += rr.y; v.z += rr.z; v.w += rr.w;
    }
    *(float4*)&C[(size_t)m * N + n] = v;
  }
}

// ---------------- attention pooling: logits -> softmax over hw -> attw
__global__ __launch_bounds__(256) void k_attnpool(const float* __restrict__ feat,
                                                  const float* __restrict__ Wattn,
                                                  float* __restrict__ attw) {
  __shared__ float S[HWn][65];
  __shared__ float Wa[NN][64];
  __shared__ float L[NN][HWn];
  __shared__ float red[4];
  const int bt = blockIdx.x, tid = threadIdx.x;
  float lacc[NN];
#pragma unroll
  for (int n = 0; n < NN; ++n) lacc[n] = 0.f;
  const float* fb = feat + (size_t)bt * HWn * Cn;
  const int srow = tid >> 4, sc4 = (tid & 15) << 2;
  for (int c0 = 0; c0 < Cn; c0 += 64) {
    for (int rr = srow; rr < HWn; rr += 16) {
      const float4 f = *(const float4*)&fb[(size_t)rr * Cn + c0 + sc4];
      S[rr][sc4] = f.x; S[rr][sc4 + 1] = f.y; S[rr][sc4 + 2] = f.z; S[rr][sc4 + 3] = f.w;
    }
    for (int idx = tid; idx < NN * 64; idx += 256)
      Wa[idx >> 6][idx & 63] = Wattn[(size_t)(idx >> 6) * Cn + c0 + (idx & 63)];
    __syncthreads();
    if (tid < HWn) {
      for (int c = 0; c < 64; ++c) {
        const float s = S[tid][c];
#pragma unroll
        for (int n = 0; n < NN; ++n) lacc[n] += Wa[n][c] * s;
      }
    }
    __syncthreads();
  }
  if (tid < HWn)
#pragma unroll
    for (int n = 0; n < NN; ++n) L[n][tid] = lacc[n];
  __syncthreads();
  for (int n = 0; n < NN; ++n) {
    const float v = (tid < HWn) ? L[n][tid] : -3.4e38f;
    const float mx = blockMax(v, red);
    const float e = (tid < HWn) ? expf(v - mx) : 0.f;
    const float s = blockSum(e, red);
    if (tid < HWn) attw[((size_t)bt * NN + n) * HWn + tid] = e / s;
  }
}

// ---------------- gf[bt,n,c] = sum_hw attw * feat
__global__ __launch_bounds__(256) void k_gf(const float* __restrict__ feat,
                                            const float* __restrict__ attw,
                                            float* __restrict__ gf) {
  __shared__ float aw[NN][HWn];
  const int bt = blockIdx.x, tid = threadIdx.x;
  for (int idx = tid; idx < NN * HWn; idx += 256)
    aw[idx / HWn][idx % HWn] = attw[(size_t)bt * NN * HWn + idx];
  __syncthreads();
  float a0[NN] = {}, a1[NN] = {};
  const float* fb = feat + (size_t)bt * HWn * Cn;
  for (int hw = 0; hw < HWn; ++hw) {
    const float f0 = fb[(size_t)hw * Cn + tid];
    const float f1 = fb[(size_t)hw * Cn + tid + 256];
#pragma unroll
    for (int n = 0; n < NN; ++n) {
      const float w = aw[n][hw];
      a0[n] += w * f0; a1[n] += w * f1;
    }
  }
#pragma unroll
  for (int n = 0; n < NN; ++n) {
    gf[((size_t)bt * NN + n) * Cn + tid] = a0[n];
    gf[((size_t)bt * NN + n) * Cn + tid + 256] = a1[n];
  }
}

// ---------------- gf2 = LN(gf @ W_gf^T + b_gf) * g1 + beta1  (one block per (bt,n))
__global__ __launch_bounds__(128) void k_gfln(const float* __restrict__ gf,
                                              const float* __restrict__ Wgf,
                                              const float* __restrict__ bgf,
                                              const float* __restrict__ g1,
                                              const float* __restrict__ beta1,
                                              float* __restrict__ gf2) {
  __shared__ __align__(16) float src[Cn];
  __shared__ float red[4];
  const int row = blockIdx.x;   // bt*9+n
  const int n = row % NN;
  const int tid = threadIdx.x;  // 128
  for (int i = tid; i < Cn; i += 128) src[i] = gf[(size_t)row * Cn + i];
  __syncthreads();
  float acc = bgf[tid];
  const float* wr = Wgf + (size_t)tid * Cn;
  for (int c = 0; c < Cn; c += 4) {
    const float4 w = *(const float4*)&wr[c];
    acc += w.x * src[c] + w.y * src[c + 1] + w.z * src[c + 2] + w.w * src[c + 3];
  }
  const float mean = blockSum(acc, red) * (1.f / 128.f);
  const float d = acc - mean;
  const float var = blockSum(d * d, red) * (1.f / 128.f);
  gf2[(size_t)row * Dn + tid] =
      d * rsqrtf(var + 1e-5f) * g1[n * Dn + tid] + beta1[n * Dn + tid];
}

// ---------------- LSTM over T=8, one block per (b,n)
__global__ __launch_bounds__(256) void k_lstm(const float* __restrict__ xW,
                                              const float* __restrict__ Whh,
                                              const float* __restrict__ bhh,
                                              float* __restrict__ ys) {
  __shared__ __align__(16) float h[Dn];
  __shared__ float cc[Dn];
  __shared__ float gates[4 * Dn];
  const int blk = blockIdx.x, b = blk / NN, n = blk % NN;
  const int tid = threadIdx.x;
  if (tid < Dn) { h[tid] = 0.f; cc[tid] = 0.f; }
  __syncthreads();
  for (int t = 0; t < 8; ++t) {
    const int bt = b * 8 + t;
    const size_t xrow = ((size_t)bt * NN + n) * (4 * Dn);
#pragma unroll
    for (int gq = 0; gq < 2; ++gq) {
      const int g = tid + gq * 256;
      float acc = xW[xrow + g] + bhh[g];
      const float* wr = Whh + (size_t)g * Dn;
#pragma unroll 8
      for (int d = 0; d < Dn; d += 4) {
        const float4 w = *(const float4*)&wr[d];
        acc += w.x * h[d] + w.y * h[d + 1] + w.z * h[d + 2] + w.w * h[d + 3];
      }
      gates[g] = acc;
    }
    __syncthreads();
    if (tid < Dn) {
      const float ig = sigm(gates[tid]);
      const float fg = sigm(gates[Dn + tid]);
      const float gg = tanhf(gates[2 * Dn + tid]);
      const float og = sigm(gates[3 * Dn + tid]);
      const float cn = fg * cc[tid] + ig * gg;
      const float hn = og * tanhf(cn);
      cc[tid] = cn; h[tid] = hn;
      ys[((size_t)bt * NN + n) * Dn + tid] = hn;
    }
    __syncthreads();
  }
}

// ---------------- offsets -> khs/kws, one block per (bt,n)
__global__ __launch_bounds__(128) void k_off(const float* __restrict__ ys,
                                             const float* __restrict__ g2,
                                             const float* __restrict__ beta2,
                                             const float* __restrict__ Wpred,
                                             const float* __restrict__ bpred,
                                             const float* __restrict__ alpha,
                                             float* __restrict__ khs,
                                             float* __restrict__ kws) {
  __shared__ float red[4];
  __shared__ float cpar[4];  // ch, cw, sh, sw
  const int row = blockIdx.x;  // bt*9+n
  const int n = row % NN;
  const int tid = threadIdx.x;
  const float y = ys[(size_t)row * Dn + tid];
  const float mean = blockSum(y, red) * (1.f / 128.f);
  const float d = y - mean;
  const float var = blockSum(d * d, red) * (1.f / 128.f);
  const float v = d * rsqrtf(var + 1e-5f) * g2[n * Dn + tid] + beta2[n * Dn + tid];
  const float o0 = blockSum(v * Wpred[0 * Dn + tid], red);
  const float o1 = blockSum(v * Wpred[1 * Dn + tid], red);
  const float o2 = blockSum(v * Wpred[2 * Dn + tid], red);
  const float o3 = blockSum(v * Wpred[3 * Dn + tid], red);
  if (tid == 0) {
    const float f0 = (o0 + bpred[0]) * alpha[0];
    const float f1 = (o1 + bpred[1]) * alpha[1];
    const float f2 = (o2 + bpred[2]) * alpha[2];
    const float f3 = (o3 + bpred[3]) * alpha[3];
    const float ph0 = ((n / 3) + 0.5f) * (14.f / 3.f);
    const float pw0 = ((n % 3) + 0.5f) * (14.f / 3.f);
    cpar[0] = ph0 + f0;
    cpar[1] = pw0 + f1;
    cpar[2] = (14.f / 3.f) * expf(f2);
    cpar[3] = (14.f / 3.f) * expf(f3);
  }
  __syncthreads();
  if (tid < 14) {
    float s = 0.f;
#pragma unroll
    for (int i = 0; i < 3; ++i) {
      const float rel = (i + 0.5f) / 3.f - 0.5f;
      const float p = cpar[0] + cpar[2] * rel;
      s += fmaxf(1.f - fabsf(p - (float)tid), 0.f);
    }
    khs[(size_t)row * 14 + tid] = s;
  } else if (tid < 28) {
    const int H = tid - 14;
    float s = 0.f;
#pragma unroll
    for (int i = 0; i < 3; ++i) {
      const float rel = (i + 0.5f) / 3.f - 0.5f;
      const float p = cpar[1] + cpar[3] * rel;
      s += fmaxf(1.f - fabsf(p - (float)H), 0.f);
    }
    kws[(size_t)row * 14 + H] = s;
  }
}

// ---------------- transpose W_kp1 [512,196] -> [196,512]
__global__ __launch_bounds__(256) void k_wkp1t(const float* __restrict__ Wkp1,
                                               float* __restrict__ wkT) {
  const int hw = blockIdx.x, c = threadIdx.x;
  wkT[(size_t)hw * Cn + c] = Wkp1[(size_t)c * HWn + hw];
  wkT[(size_t)hw * Cn + c + 256] = Wkp1[(size_t)(c + 256) * HWn + hw];
}

// ---------------- nodes = samp + kern2d @ W_kp1^T + b_kp1  (one block per bt)
__global__ __launch_bounds__(256) void k_nodes(const float* __restrict__ feat,
                                               const float* __restrict__ wkT,
                                               const float* __restrict__ khs,
                                               const float* __restrict__ kws,
                                               const float* __restrict__ bkp1,
                                               float* __restrict__ nodes) {
  __shared__ float kh[NN][14], kw[NN][14];
  const int bt = blockIdx.x, tid = threadIdx.x;
  if (tid < NN * 14) {
    kh[tid / 14][tid % 14] = khs[(size_t)bt * NN * 14 + tid];
    kw[tid / 14][tid % 14] = kws[(size_t)bt * NN * 14 + tid];
  }
  __syncthreads();
  float a0[NN] = {}, a1[NN] = {};
  const float* fb = feat + (size_t)bt * HWn * Cn;
  for (int hw = 0; hw < HWn; ++hw) {
    const int Hh = hw / 14, Ll = hw % 14;
    const float f0 = fb[(size_t)hw * Cn + tid] * (1.f / 9.f) + wkT[(size_t)hw * Cn + tid];
    const float f1 = fb[(size_t)hw * Cn + tid + 256] * (1.f / 9.f) + wkT[(size_t)hw * Cn + tid + 256];
#pragma unroll
    for (int n = 0; n < NN; ++n) {
      const float w = kh[n][Hh] * kw[n][Ll];
      a0[n] += w * f0; a1[n] += w * f1;
    }
  }
#pragma unroll
  for (int n = 0; n < NN; ++n) {
    nodes[((size_t)bt * NN + n) * Cn + tid] = a0[n] + bkp1[tid];
    nodes[((size_t)bt * NN + n) * Cn + tid + 256] = a1[n] + bkp1[tid + 256];
  }
}

// ---------------- per-(b,t) 9x9 graph attention: agg = softmax(qk^T/sqrt(C)) v
__global__ __launch_bounds__(256) void k_att(const float* __restrict__ q,
                                             const float* __restrict__ k,
                                             const float* __restrict__ v,
                                             float* __restrict__ agg) {
  __shared__ __align__(16) float qs[NN][Cn];
  __shared__ __align__(16) float ks[NN][Cn];
  __shared__ __align__(16) float vs[NN][Cn];
  __shared__ float s[NN][NN];
  const int bt = blockIdx.x, tid = threadIdx.x;
  const size_t base = (size_t)bt * NN * Cn;
  for (int idx = tid; idx < NN * Cn; idx += 256) {
    qs[idx / Cn][idx % Cn] = q[base + idx];
    ks[idx / Cn][idx % Cn] = k[base + idx];
    vs[idx / Cn][idx % Cn] = v[base + idx];
  }
  __syncthreads();
  if (tid < NN * NN) {
    const int i = tid / NN, j = tid % NN;
    float acc = 0.f;
    for (int c = 0; c < Cn; c += 4) {
      const float4 qa = *(const float4*)&qs[i][c];
      const float4 kb = *(const float4*)&ks[j][c];
      acc += qa.x * kb.x + qa.y * kb.y + qa.z * kb.z + qa.w * kb.w;
    }
    s[i][j] = acc * 0.044194173824159216f;  // 1/sqrt(512)
  }
  __syncthreads();
  if (tid < NN) {
    float mx = -3.4e38f;
#pragma unroll
    for (int j = 0; j < NN; ++j) mx = fmaxf(mx, s[tid][j]);
    float sum = 0.f;
#pragma unroll
    for (int j = 0; j < NN; ++j) { const float e = expf(s[tid][j] - mx); s[tid][j] = e; sum += e; }
    const float inv = 1.f / sum;
#pragma unroll
    for (int j = 0; j < NN; ++j) s[tid][j] *= inv;
  }
  __syncthreads();
  for (int c = tid; c < Cn; c += 256) {
#pragma unroll
    for (int i = 0; i < NN; ++i) {
      float acc = 0.f;
#pragma unroll
      for (int j = 0; j < NN; ++j) acc += s[i][j] * vs[j][c];
      agg[((size_t)bt * NN + i) * Cn + c] = acc;
    }
  }
}

// ---------------- GRU elementwise update
template <int T0>
__global__ __launch_bounds__(256) void k_gruupd(const float* __restrict__ gi,
                                                const float* __restrict__ gh,
                                                const float* __restrict__ bghh,
                                                float* __restrict__ hgru,
                                                float* __restrict__ out_nodes,
                                                int t) {
  const int idx = blockIdx.x * 256 + threadIdx.x;  // 144*512
  const int row = idx >> 9, d = idx & 511;
  const int b = row / NN, n = row % NN;
  const size_t girow = ((size_t)(b * 8 + t) * NN + n) * (3 * Cn);
  const float ir = gi[girow + d], iz = gi[girow + Cn + d], ig = gi[girow + 2 * Cn + d];
  float hr, hz, hg, hp;
  if (T0) {
    hr = bghh[d]; hz = bghh[Cn + d]; hg = bghh[2 * Cn + d]; hp = 0.f;
  } else {
    const size_t gr = (size_t)row * (3 * Cn);
    hr = gh[gr + d]; hz = gh[gr + Cn + d]; hg = gh[gr + 2 * Cn + d];
    hp = hgru[(size_t)row * Cn + d];
  }
  const float rg = sigm(ir + hr);
  const float zg = sigm(iz + hz);
  const float ng = tanhf(ig + rg * hg);
  const float h = (1.f - zg) * ng + zg * hp;
  hgru[(size_t)row * Cn + d] = h;
  out_nodes[((size_t)(b * 8 + t) * NN + n) * Cn + d] = h;
}

// ---------------- remap nodes to spatial map: om[r, c] = num/den (bf16 out)
__global__ __launch_bounds__(256) void k_remap(const float* __restrict__ out_nodes,
                                               const float* __restrict__ khs,
                                               const float* __restrict__ kws,
                                               u16* __restrict__ om) {
  __shared__ __align__(16) float on[NN][Cn];
  __shared__ float kh[NN][14], kw[NN][14];
  const int bt = blockIdx.x, tid = threadIdx.x;
  for (int idx = tid; idx < NN * Cn; idx += 256)
    on[idx / Cn][idx % Cn] = out_nodes[(size_t)bt * NN * Cn + idx];
  if (tid < NN * 14) {
    kh[tid / 14][tid % 14] = khs[(size_t)bt * NN * 14 + tid];
    kw[tid / 14][tid % 14] = kws[(size_t)bt * NN * 14 + tid];
  }
  __syncthreads();
  for (int hw = 0; hw < HWn; ++hw) {
    const int Hh = hw / 14, Ll = hw % 14;
    float w[NN];
    float den = 1e-6f;
#pragma unroll
    for (int n = 0; n < NN; ++n) { w[n] = kh[n][Hh] * kw[n][Ll]; den += w[n]; }
    const float inv = 1.f / den;
    float s0 = 0.f, s1 = 0.f;
#pragma unroll
    for (int n = 0; n < NN; ++n) {
      s0 += on[n][tid] * w[n];
      s1 += on[n][tid + 256] * w[n];
    }
    om[((size_t)bt * HWn + hw) * Cn + tid] = f2bf(s0 * inv);
    om[((size_t)bt * HWn + hw) * Cn + tid + 256] = f2bf(s1 * inv);
  }
}

extern "C" void kernel_launch(void* const* d_in, const int* in_sizes, int n_in,
                              void* d_out, int out_size, void* d_ws, size_t ws_size,
                              hipStream_t stream) {
  const float* x      = (const float*)d_in[0];
  const float* W_proj = (const float*)d_in[1];
  const float* b_proj = (const float*)d_in[2];
  const float* W_attn = (const float*)d_in[3];
  const float* W_gf   = (const float*)d_in[4];
  const float* b_gf   = (const float*)d_in[5];
  const float* g1     = (const float*)d_in[6];
  const float* beta1  = (const float*)d_in[7];
  const float* g2     = (const float*)d_in[8];
  const float* beta2  = (const float*)d_in[9];
  const float* W_ih   = (const float*)d_in[10];
  const float* W_hh   = (const float*)d_in[11];
  const float* b_ih   = (const float*)d_in[12];
  const float* b_hh   = (const float*)d_in[13];
  const float* W_pred = (const float*)d_in[14];
  const float* b_pred = (const float*)d_in[15];
  const float* alpha  = (const float*)d_in[16];
  const float* W_kp1  = (const float*)d_in[17];
  const float* b_kp1  = (const float*)d_in[18];
  const float* Wq     = (const float*)d_in[19];
  const float* Wk     = (const float*)d_in[20];
  const float* Wv     = (const float*)d_in[21];
  const float* Wu     = (const float*)d_in[22];
  const float* b_u    = (const float*)d_in[23];
  const float* W_gih  = (const float*)d_in[24];
  const float* W_ghh  = (const float*)d_in[25];
  const float* b_gih  = (const float*)d_in[26];
  const float* b_ghh  = (const float*)d_in[27];
  const float* W_back = (const float*)d_in[28];
  const float* b_back = (const float*)d_in[29];
  float* out = (float*)d_out;

  float* ws = (float*)d_ws;
  // region 0: feat fp32 [25088,512] (later aliased by om bf16)
  float* feat = ws;                       // 12,845,056 floats
  u16* om16 = (u16*)feat;
  // region 1: pool (12,845,056 floats). First holds xT bf16 (whole region);
  // after k_mm128<0> consumes xT, the small buffers below alias it.
  float* pool = ws + 12845056;
  u16* xT = (u16*)pool;                   // 25,690,112 bf16
  size_t off = 0;
  float* attw      = pool + off; off += (size_t)BTn * NN * HWn;
  float* gf        = pool + off; off += (size_t)BTn * NN * Cn;
  float* gf2       = pool + off; off += (size_t)BTn * NN * Dn;
  float* xW        = pool + off; off += (size_t)BTn * NN * 512;
  float* ys        = pool + off; off += (size_t)BTn * NN * Dn;
  float* khs       = pool + off; off += (size_t)BTn * NN * 14;
  float* kws       = pool + off; off += (size_t)BTn * NN * 14;
  float* nodes     = pool + off; off += (size_t)BTn * NN * Cn;
  float* qb        = pool + off; off += (size_t)BTn * NN * Cn;
  float* kb        = pool + off; off += (size_t)BTn * NN * Cn;
  float* vb        = pool + off; off += (size_t)BTn * NN * Cn;
  float* aggb      = pool + off; off += (size_t)BTn * NN * Cn;
  float* nd2       = pool + off; off += (size_t)BTn * NN * Cn;
  float* gi        = pool + off; off += (size_t)BTn * NN * 3 * Cn;
  float* hgru      = pool + off; off += (size_t)144 * Cn;
  float* gh        = pool + off; off += (size_t)144 * 3 * Cn;
  float* wkT       = pool + off; off += (size_t)HWn * Cn;
  float* out_nodes = pool + off; off += (size_t)BTn * NN * Cn;
  // region 2: bf16 weights
  u16* Wpb = (u16*)(ws + 25690112);       // 524,288 bf16
  u16* Wbb = (u16*)(ws + 25952256);       // 524,288 bf16

  // 0. weight casts + x transpose/cast
  k_cast<<<512, 256, 0, stream>>>(W_proj, Wpb, 524288);
  k_cast<<<512, 256, 0, stream>>>(W_back, Wbb, 524288);
  k_xt<<<dim3(128, 16), 256, 0, stream>>>(x, xT);
  // 1. backbone projection (bf16 MFMA): feat[r=(bt,hw), o]
  k_mm128<0><<<dim3(196, 4), 256, 0, stream>>>(xT, Wpb, b_proj, nullptr, feat, 25088, 512, 1024);
  // 2. attention pooling weights
  k_attnpool<<<BTn, 256, 0, stream>>>(feat, W_attn, attw);
  // 3. gf = attw-weighted pooling of feat
  k_gf<<<BTn, 256, 0, stream>>>(feat, attw, gf);
  // 4. gf2 = LN(gf @ W_gf^T + b_gf)
  k_gfln<<<BTn * NN, 128, 0, stream>>>(gf, W_gf, b_gf, g1, beta1, gf2);
  // 5. LSTM input GEMM
  k_gemm<1, 0, 0><<<dim3(18, 8), 256, 0, stream>>>(gf2, W_ih, b_ih, nullptr, xW, 1152, 512, 128);
  // 6. LSTM recurrence
  k_lstm<<<144, 256, 0, stream>>>(xW, W_hh, b_hh, ys);
  // 7. offsets -> sampling kernels
  k_off<<<BTn * NN, 128, 0, stream>>>(ys, g2, beta2, W_pred, b_pred, alpha, khs, kws);
  // 8. transpose W_kp1
  k_wkp1t<<<HWn, 256, 0, stream>>>(W_kp1, wkT);
  // 9. nodes = crop-pool + kernel-location embedding
  k_nodes<<<BTn, 256, 0, stream>>>(feat, wkT, khs, kws, b_kp1, nodes);
  // 10. q/k/v projections
  k_gemm<0, 0, 0><<<dim3(18, 8), 256, 0, stream>>>(nodes, Wq, nullptr, nullptr, qb, 1152, 512, 512);
  k_gemm<0, 0, 0><<<dim3(18, 8), 256, 0, stream>>>(nodes, Wk, nullptr, nullptr, kb, 1152, 512, 512);
  k_gemm<0, 0, 0><<<dim3(18, 8), 256, 0, stream>>>(nodes, Wv, nullptr, nullptr, vb, 1152, 512, 512);
  // 11. 9x9 graph attention
  k_att<<<BTn, 256, 0, stream>>>(qb, kb, vb, aggb);
  // 12. nd2 = nodes + relu(agg @ Wu^T + b_u)
  k_gemm<1, 1, 1><<<dim3(18, 8), 256, 0, stream>>>(aggb, Wu, b_u, nodes, nd2, 1152, 512, 512);
  // 13. GRU input GEMM
  k_gemm<1, 0, 0><<<dim3(18, 24), 256, 0, stream>>>(nd2, W_gih, b_gih, nullptr, gi, 1152, 1536, 512);
  // 14. GRU recurrence
  for (int t = 0; t < 8; ++t) {
    if (t > 0)
      k_gemm<1, 0, 0><<<dim3(3, 24), 256, 0, stream>>>(hgru, W_ghh, b_ghh, nullptr, gh, 144, 1536, 512);
    if (t == 0)
      k_gruupd<1><<<288, 256, 0, stream>>>(gi, gh, b_ghh, hgru, out_nodes, t);
    else
      k_gruupd<0><<<288, 256, 0, stream>>>(gi, gh, b_ghh, hgru, out_nodes, t);
  }
  // 15. remap node states to spatial map (bf16 om aliases feat region)
  k_remap<<<BTn, 256, 0, stream>>>(out_nodes, khs, kws, om16);
  // 16. project back + residual (bf16 MFMA, fused epilogue)
  k_mm128<1><<<dim3(196, 8), 256, 0, stream>>>(om16, Wbb, b_back, x, out, 25088, 1024, 512);
}